// Round 2
// baseline (365.257 us; speedup 1.0000x reference)
//
#include <hip/hip_runtime.h>
#include <hip/hip_bf16.h>

// VectorQuantizer on MI355X (gfx950), round 2.
// argmin_k ||e_k||^2 - 2 x.e_k via bf16 MFMA 16x16x32.
// R2: 33 KB LDS (4 blocks/CU), A-frags global->reg, k-major codebook with
// global_load_lds width-16 staging (conflict-free ds_read_b128 B-frags),
// vectorized phase-2 gather/loss/transpose.

#define DIN 256
#define NCODES 1024

typedef __attribute__((ext_vector_type(8))) short short8;
typedef __attribute__((ext_vector_type(4))) float float4v;
typedef __attribute__((ext_vector_type(2))) float float2v;
typedef __attribute__((ext_vector_type(4))) unsigned short ushort4v;

static __device__ __forceinline__ unsigned short f2bf(float f) {
  unsigned int u = __float_as_uint(f);
  unsigned int r = (u + 0x7fffu + ((u >> 16) & 1u)) >> 16;  // RNE
  return (unsigned short)r;
}

// ---- prep: codebook fp32 -> bf16 k-major [chunk8][code][8] + norms ----
__global__ void vq_prep(const float* __restrict__ e,
                        unsigned short* __restrict__ e_bf2,
                        float* __restrict__ norms) {
  int wave = threadIdx.x >> 6, lane = threadIdx.x & 63;
  int k = blockIdx.x * 4 + wave;               // 256 blocks * 4 codes
  float4v v = ((const float4v*)(e + k * DIN))[lane];
  float ss = v[0]*v[0] + v[1]*v[1] + v[2]*v[2] + v[3]*v[3];
  ushort4v pk;
  pk[0] = f2bf(v[0]); pk[1] = f2bf(v[1]); pk[2] = f2bf(v[2]); pk[3] = f2bf(v[3]);
  int cc = lane >> 1, sub = lane & 1;          // d-chunk of 8, half
  *(ushort4v*)(e_bf2 + (cc * NCODES + k) * 8 + sub * 4) = pk;
  #pragma unroll
  for (int m = 1; m < 64; m <<= 1) ss += __shfl_xor(ss, m, 64);
  if (lane == 0) norms[k] = ss;
}

// ---- main: per (b,h) line: 64 rows x 1024 codes argmin + output + loss ----
__global__ void __launch_bounds__(256, 4)
vq_main(const float* __restrict__ xin, const float* __restrict__ e_fp,
        const unsigned short* __restrict__ e_bf2, const float* __restrict__ norms,
        float* __restrict__ out, float* __restrict__ loss_acc) {
  __shared__ char smem[34080];
  unsigned short* es = (unsigned short*)smem;    // [32 k-chunks][64 codes][8] = 32 KB
  float* qs  = (float*)smem;                     // [64 d][66] fp32 transpose buf
  float* vs  = (float*)(smem + 32768);           // [64][2] best vals
  int*   is_ = (int*)  (smem + 33280);           // [64][2] best idx
  int*   fi  = (int*)  (smem + 33792);           // [64] final idx
  float* rs  = (float*)(smem + 34048);           // [4] loss partials

  const int tid  = threadIdx.x;
  const int wave = tid >> 6, lane = tid & 63;
  const int m16  = lane & 15, quad = lane >> 4;
  const int wr   = wave >> 1, wc = wave & 1;     // wave tile: 32 rows x 32 cols
  const int b    = blockIdx.x >> 6, h = blockIdx.x & 63;
  const int base = b * 1048576 + h * 64;         // + d*4096 + w

  // ---- A fragments: direct global -> register, bf16 ----
  short8 areg[16];
  #pragma unroll
  for (int i = 0; i < 2; ++i) {
    int r = wr * 32 + i * 16 + m16;
    #pragma unroll
    for (int kk = 0; kk < 8; ++kk) {
      int cc = kk * 4 + quad;
      short8 pk;
      #pragma unroll
      for (int ii = 0; ii < 8; ++ii)
        pk[ii] = (short)f2bf(xin[base + (cc * 8 + ii) * 4096 + r]);
      areg[i * 8 + kk] = pk;
    }
  }

  float bestv[2][4];
  int   besti[2][4];
  float4v acc[2][2];
  #pragma unroll
  for (int i = 0; i < 2; ++i) {
    #pragma unroll
    for (int r = 0; r < 4; ++r) { bestv[i][r] = INFINITY; besti[i][r] = 0; }
    #pragma unroll
    for (int j = 0; j < 2; ++j) acc[i][j] = (float4v)(0.0f);
  }

  // ---- 16 code tiles of 64 ----
  for (int ct = 0; ct < 16; ++ct) {
    int c0 = ct * 64;
    // async stage: 8x 1KB per wave, contiguous global -> contiguous LDS
    #pragma unroll
    for (int q = 0; q < 8; ++q) {
      int cc8 = wave * 8 + q;
      const unsigned short* gsrc = e_bf2 + (cc8 * NCODES + c0) * 8 + lane * 8;
      unsigned short* ldst = es + cc8 * 512;     // wave-uniform base
      __builtin_amdgcn_global_load_lds(
          (const __attribute__((address_space(1))) void*)gsrc,
          (__attribute__((address_space(3))) void*)ldst, 16, 0, 0);
    }
    __syncthreads();
    #pragma unroll
    for (int kk = 0; kk < 8; ++kk) {
      int cc = kk * 4 + quad;
      short8 b0 = *(short8*)(es + (cc * 64 + wc * 32 + m16) * 8);
      short8 b1 = *(short8*)(es + (cc * 64 + wc * 32 + 16 + m16) * 8);
      acc[0][0] = __builtin_amdgcn_mfma_f32_16x16x32_bf16(areg[kk],     b0, acc[0][0], 0, 0, 0);
      acc[0][1] = __builtin_amdgcn_mfma_f32_16x16x32_bf16(areg[kk],     b1, acc[0][1], 0, 0, 0);
      acc[1][0] = __builtin_amdgcn_mfma_f32_16x16x32_bf16(areg[8 + kk], b0, acc[1][0], 0, 0, 0);
      acc[1][1] = __builtin_amdgcn_mfma_f32_16x16x32_bf16(areg[8 + kk], b1, acc[1][1], 0, 0, 0);
    }
    // epilogue: fold norms, running argmin (cols ascend over ct/j -> strict <)
    #pragma unroll
    for (int j = 0; j < 2; ++j) {
      int col = c0 + wc * 32 + j * 16 + m16;
      float nj = norms[col];
      #pragma unroll
      for (int i = 0; i < 2; ++i) {
        #pragma unroll
        for (int r = 0; r < 4; ++r) {
          float s = nj - 2.0f * acc[i][j][r];
          if (s < bestv[i][r]) { bestv[i][r] = s; besti[i][r] = col; }
        }
        acc[i][j] = (float4v)(0.0f);
      }
    }
    __syncthreads();
  }

  // ---- cross-lane argmin over 16 col-lanes (tie -> smaller idx) ----
  #pragma unroll
  for (int msk = 1; msk <= 8; msk <<= 1) {
    #pragma unroll
    for (int i = 0; i < 2; ++i)
      #pragma unroll
      for (int r = 0; r < 4; ++r) {
        float ov = __shfl_xor(bestv[i][r], msk, 64);
        int   oi = __shfl_xor(besti[i][r], msk, 64);
        if (ov < bestv[i][r] || (ov == bestv[i][r] && oi < besti[i][r])) {
          bestv[i][r] = ov; besti[i][r] = oi;
        }
      }
  }
  if (m16 == 0) {
    #pragma unroll
    for (int i = 0; i < 2; ++i)
      #pragma unroll
      for (int r = 0; r < 4; ++r) {
        int rl = wr * 32 + i * 16 + quad * 4 + r;
        vs [rl * 2 + wc] = bestv[i][r];
        is_[rl * 2 + wc] = besti[i][r];
      }
  }
  __syncthreads();
  if (tid < 64) {
    float v0 = vs[tid * 2], v1 = vs[tid * 2 + 1];
    int   i0 = is_[tid * 2], i1 = is_[tid * 2 + 1];
    fi[tid] = (v1 < v0 || (v1 == v0 && i1 < i0)) ? i1 : i0;
  }
  __syncthreads();

  // ---- phase 2: gather exact fp32 e rows, LDS transpose, write + loss ----
  float lsum = 0.0f;
  const int wq = tid & 31, dL0 = tid >> 5;       // write/loss mapping
  for (int h2 = 0; h2 < 4; ++h2) {               // 4 chunks of 64 d
    #pragma unroll
    for (int j = 0; j < 4; ++j) {                // gather + transpose 64w x 64d
      int f = j * 256 + tid;
      int w2 = f >> 4, cc = f & 15;
      int idx = fi[w2];
      float4v qv = *(const float4v*)(e_fp + idx * DIN + h2 * 64 + cc * 4);
      #pragma unroll
      for (int ii = 0; ii < 4; ++ii)
        qs[(cc * 4 + ii) * 66 + w2] = qv[ii];
    }
    __syncthreads();
    #pragma unroll
    for (int dd = 0; dd < 8; ++dd) {             // coalesced writes + exact loss
      int dL = dd * 8 + dL0;
      int g = base + (h2 * 64 + dL) * 4096 + wq * 2;
      float2v q  = *(float2v*)(qs + dL * 66 + wq * 2);
      float2v xv = *(const float2v*)(xin + g);
      out[1 + g] = q[0];
      out[2 + g] = q[1];
      float d0 = q[0] - xv[0], d1 = q[1] - xv[1];
      lsum += d0 * d0 + d1 * d1;
    }
    __syncthreads();
  }

  #pragma unroll
  for (int msk = 1; msk < 64; msk <<= 1) lsum += __shfl_xor(lsum, msk, 64);
  if (lane == 0) rs[wave] = lsum;
  __syncthreads();
  if (tid == 0) atomicAdd(loss_acc, rs[0] + rs[1] + rs[2] + rs[3]);
}

__global__ void vq_fin(const float* __restrict__ loss_acc,
                       const float* __restrict__ beta,
                       float* __restrict__ out) {
  out[0] = (1.0f + beta[0]) * loss_acc[0] / 33554432.0f;
}

extern "C" void kernel_launch(void* const* d_in, const int* in_sizes, int n_in,
                              void* d_out, int out_size, void* d_ws, size_t ws_size,
                              hipStream_t stream) {
  const float* xin  = (const float*)d_in[0];
  const float* emb  = (const float*)d_in[1];
  const float* beta = (const float*)d_in[2];
  float* out = (float*)d_out;
  float* loss_acc = (float*)d_ws;                                // 4 B
  float* norms = (float*)((char*)d_ws + 4096);                   // 4 KB
  unsigned short* e_bf2 = (unsigned short*)((char*)d_ws + 8192); // 512 KB k-major

  hipMemsetAsync(d_ws, 0, 4, stream);
  vq_prep<<<256, 256, 0, stream>>>(emb, e_bf2, norms);
  vq_main<<<2048, 256, 0, stream>>>(xin, emb, e_bf2, norms, out, loss_acc);
  vq_fin<<<1, 1, 0, stream>>>(loss_acc, beta, out);
}